// Round 1
// 1397.257 us; speedup vs baseline: 9.9124x; 9.9124x over previous
//
#include <hip/hip_runtime.h>
#include <stdint.h>
#include <stddef.h>

// Swin WindowAttention, MFMA bf16 rewrite.
// B=8, H=W=128, C=512, WS=8 -> 2048 windows x 64 tokens; NH=16, hd=32.
// Prepass: transpose+cast qkv_w/proj_w to bf16 K-major in d_ws (2 MiB).
// Main: 1 window/block, 256 thr (4 waves), v_mfma_f32_16x16x32_bf16 everywhere.

typedef unsigned short ushort_t;
typedef __attribute__((ext_vector_type(8))) unsigned short ushort8;
typedef __attribute__((ext_vector_type(8))) short short8;   // 8 bf16 = 4 VGPR (MFMA A/B frag)
typedef __attribute__((ext_vector_type(4))) float f32x4;    // MFMA C/D frag

__device__ __forceinline__ float bf2f(ushort_t u) {
    union { unsigned int i; float f; } x; x.i = ((unsigned int)u) << 16; return x.f;
}
__device__ __forceinline__ ushort_t f2bf(float f) {
    union { float f; unsigned int i; } x; x.f = f;
    unsigned int r = x.i + 0x7fffu + ((x.i >> 16) & 1u);    // RNE
    return (ushort_t)(r >> 16);
}

// ---------------- prepass: W (fp32 [c][o]) -> W_t (bf16 [o][c]) ----------------
__global__ __launch_bounds__(256)
void wtrans(const float* __restrict__ qkv_w, const float* __restrict__ proj_w,
            ushort_t* __restrict__ wq_t, ushort_t* __restrict__ wp_t)
{
    __shared__ ushort_t t[64 * 65];
    const int bid = blockIdx.x, tid = threadIdx.x;
    const float* src; ushort_t* dst; int W, to, tc;
    if (bid < 192) { src = qkv_w; dst = wq_t; W = 1536; to = bid % 24; tc = bid / 24; }
    else { int r = bid - 192; src = proj_w; dst = wp_t; W = 512; to = r & 7; tc = r >> 3; }
    for (int l = 0; l < 16; ++l) {
        int idx = l * 256 + tid; int cr = idx >> 6, oc = idx & 63;
        t[oc * 65 + cr] = f2bf(src[(size_t)(tc * 64 + cr) * W + to * 64 + oc]);
    }
    __syncthreads();
    for (int l = 0; l < 16; ++l) {
        int idx = l * 256 + tid; int orr = idx >> 6, cc = idx & 63;
        dst[(size_t)(to * 64 + orr) * 512 + tc * 64 + cc] = t[orr * 65 + cc];
    }
}

// ---------------- main fused kernel ----------------
// LDS map (bytes):
//   xs  @0      : X bf16 [64][512], row 1024B, XOR swizzle ((tok&7)<<4)    65536
//   ao  @65536  : attn-out bf16 [64][512], same layout                     65536
//   rg  @131072 : 24576-byte region, time-multiplexed:
//     QKV phase : w4 [4 heads][96 n][32 k] bf16, row 64B, swz ((n&3)<<4)
//     attn phase: qh [64][40]B=80B-row @+0 (5120) | kh @+5120 (5120)
//                 vt [32 d][64 tok] swz ((d&7)<<4) @+10240 (4096)
//                 ps [64][64] swz ((row&7)<<4) @+14336 (8192)
//     proj phase: wpc [512 n][32 k] (in xs region), row 64B, swz ((n&3)<<4)
#define SM_XS 0
#define SM_AO 65536
#define SM_RG 131072
#define SM_QH (SM_RG)
#define SM_KH (SM_RG + 5120)
#define SM_VT (SM_RG + 10240)
#define SM_PS (SM_RG + 14336)
#define SMEM_BYTES 155648

__global__ __launch_bounds__(256, 1)
void swin_mfma(const float* __restrict__ xg,
               const ushort_t* __restrict__ wq_t,
               const float* __restrict__ qkv_b,
               const ushort_t* __restrict__ wp_t,
               const float* __restrict__ proj_b,
               const float* __restrict__ btab,
               float* __restrict__ outg)
{
    extern __shared__ char smem[];
    const int tid = threadIdx.x;
    const int wv = tid >> 6;          // wave 0..3
    const int lane = tid & 63;
    const int l4 = lane >> 4;         // frag k-group
    const int l16 = lane & 15;        // frag row/col
    const int blk = blockIdx.x;
    const int b = blk >> 8, wy = (blk >> 4) & 15, wx = blk & 15;
    const f32x4 fzero = {0.f, 0.f, 0.f, 0.f};
    const float scale = 0.17677669529663687f;   // 1/sqrt(32)

    // ---- stage X window (fp32 -> bf16, swizzled) ----
    #pragma unroll
    for (int l = 0; l < 16; ++l) {
        int idx = l * 256 + tid;
        int t = idx >> 6, v = idx & 63;
        int ty = t >> 3, tx = t & 7;
        size_t goff = ((size_t)((b * 128 + wy * 8 + ty) * 128 + wx * 8 + tx)) * 512 + v * 8;
        float4 a0 = *(const float4*)(xg + goff);
        float4 a1 = *(const float4*)(xg + goff + 4);
        ushort8 d;
        d[0] = f2bf(a0.x); d[1] = f2bf(a0.y); d[2] = f2bf(a0.z); d[3] = f2bf(a0.w);
        d[4] = f2bf(a1.x); d[5] = f2bf(a1.y); d[6] = f2bf(a1.z); d[7] = f2bf(a1.w);
        *(ushort8*)(smem + SM_XS + t * 1024 + ((v * 16) ^ ((t & 7) << 4))) = d;
    }

    // ================= QKV + attention, 4 heads per iter (wave = head) =================
    for (int hi = 0; hi < 4; ++hi) {
        const int h = hi * 4 + wv;
        f32x4 acc[4][6];                       // [m-tile][n-tile: q0 q1 k0 k1 v0 v1]
        #pragma unroll
        for (int mt = 0; mt < 4; ++mt)
            #pragma unroll
            for (int nt = 0; nt < 6; ++nt) acc[mt][nt] = fzero;

        // per-thread staging descriptors: 4 heads x 96 n x 32 k per chunk = 6 ushort8/thread
        int stg_go[6], stg_lo[6];
        #pragma unroll
        for (int l = 0; l < 6; ++l) {
            int idx = l * 256 + tid;
            int hw = idx / 384, rem = idx % 384;
            int n = rem >> 2, cg = rem & 3;
            int o = (n >> 5) * 512 + (hi * 4 + hw) * 32 + (n & 31);   // qkv_w col
            stg_go[l] = o * 1024 + cg * 16;                            // byte off in wq_t
            stg_lo[l] = SM_RG + hw * 6144 + n * 64 + ((cg * 16) ^ ((n & 3) << 4));
        }
        ushort8 stg[6];
        #pragma unroll
        for (int l = 0; l < 6; ++l)
            stg[l] = *(const ushort8*)((const char*)wq_t + stg_go[l]);

        for (int kc = 0; kc < 16; ++kc) {      // K chunks of 32
            __syncthreads();                    // region free (prev mfma/attn done)
            #pragma unroll
            for (int l = 0; l < 6; ++l)
                *(ushort8*)(smem + stg_lo[l]) = stg[l];
            if (kc < 15) {                      // prefetch next chunk (hides global latency)
                #pragma unroll
                for (int l = 0; l < 6; ++l)
                    stg[l] = *(const ushort8*)((const char*)wq_t + stg_go[l] + (kc + 1) * 64);
            }
            __syncthreads();
            short8 afr[4];
            #pragma unroll
            for (int mt = 0; mt < 4; ++mt) {
                int m = mt * 16 + l16;
                afr[mt] = *(const short8*)(smem + SM_XS + m * 1024 +
                                           ((kc * 64 + l4 * 16) ^ ((m & 7) << 4)));
            }
            #pragma unroll
            for (int nt = 0; nt < 6; ++nt) {
                int n = nt * 16 + l16;
                short8 bfr = *(const short8*)(smem + SM_RG + wv * 6144 + n * 64 +
                                              ((l4 * 16) ^ ((n & 3) << 4)));
                #pragma unroll
                for (int mt = 0; mt < 4; ++mt)
                    acc[mt][nt] = __builtin_amdgcn_mfma_f32_16x16x32_bf16(afr[mt], bfr, acc[mt][nt], 0, 0, 0);
            }
        }
        __syncthreads();                        // all waves done with w4 before parks

        float bq[2], bk_[2], bv_[2];
        #pragma unroll
        for (int i = 0; i < 2; ++i) {
            bq[i]  = qkv_b[         h * 32 + i * 16 + l16];
            bk_[i] = qkv_b[ 512  +  h * 32 + i * 16 + l16];
            bv_[i] = qkv_b[ 1024 +  h * 32 + i * 16 + l16];
        }

        // ---- attention, head-serial across the 4 waves ----
        for (int sub = 0; sub < 4; ++sub) {
            if (wv == sub) {                    // owner parks its Q(scaled)/K/V
                #pragma unroll
                for (int mt = 0; mt < 4; ++mt) {
                    #pragma unroll
                    for (int r = 0; r < 4; ++r) {
                        int tok = mt * 16 + l4 * 4 + r;   // C-layout row
                        #pragma unroll
                        for (int i = 0; i < 2; ++i) {
                            int d = i * 16 + l16;          // C-layout col
                            *(ushort_t*)(smem + SM_QH + tok * 80 + d * 2) =
                                f2bf((acc[mt][i][r] + bq[i]) * scale);
                            *(ushort_t*)(smem + SM_KH + tok * 80 + d * 2) =
                                f2bf(acc[mt][i + 2][r] + bk_[i]);
                            *(ushort_t*)(smem + SM_VT + d * 128 + ((tok * 2) ^ ((d & 7) << 4))) =
                                f2bf(acc[mt][i + 4][r] + bv_[i]);
                        }
                    }
                }
            }
            __syncthreads();
            const int hh = hi * 4 + sub;

            // S = Q K^T (+bias), wave wv owns rows [wv*16, wv*16+16)
            short8 aq = *(const short8*)(smem + SM_QH + (wv * 16 + l16) * 80 + l4 * 16);
            f32x4 sv[4];
            #pragma unroll
            for (int nt = 0; nt < 4; ++nt) {
                short8 bkf = *(const short8*)(smem + SM_KH + (nt * 16 + l16) * 80 + l4 * 16);
                sv[nt] = __builtin_amdgcn_mfma_f32_16x16x32_bf16(aq, bkf, fzero, 0, 0, 0);
            }
            #pragma unroll
            for (int nt = 0; nt < 4; ++nt) {
                int col = nt * 16 + l16;
                #pragma unroll
                for (int r = 0; r < 4; ++r) {
                    int row = wv * 16 + l4 * 4 + r;
                    int dy = (row >> 3) - (col >> 3) + 7;
                    int dx = (row & 7)  - (col & 7)  + 7;
                    sv[nt][r] += btab[(dy * 15 + dx) * 16 + hh];
                }
            }
            // wave-parallel softmax: row r lives across l16 (16 lanes) x 4 col-tiles
            #pragma unroll
            for (int r = 0; r < 4; ++r) {
                float mx = fmaxf(fmaxf(sv[0][r], sv[1][r]), fmaxf(sv[2][r], sv[3][r]));
                mx = fmaxf(mx, __shfl_xor(mx, 1));
                mx = fmaxf(mx, __shfl_xor(mx, 2));
                mx = fmaxf(mx, __shfl_xor(mx, 4));
                mx = fmaxf(mx, __shfl_xor(mx, 8));
                float sm = 0.f;
                #pragma unroll
                for (int nt = 0; nt < 4; ++nt) { sv[nt][r] = __expf(sv[nt][r] - mx); sm += sv[nt][r]; }
                sm += __shfl_xor(sm, 1);
                sm += __shfl_xor(sm, 2);
                sm += __shfl_xor(sm, 4);
                sm += __shfl_xor(sm, 8);
                float inv = 1.f / sm;
                #pragma unroll
                for (int nt = 0; nt < 4; ++nt) sv[nt][r] *= inv;
            }
            // P -> LDS bf16 (own rows only; intra-wave reuse, no barrier needed)
            #pragma unroll
            for (int nt = 0; nt < 4; ++nt) {
                int col = nt * 16 + l16;
                #pragma unroll
                for (int r = 0; r < 4; ++r) {
                    int row = wv * 16 + l4 * 4 + r;
                    *(ushort_t*)(smem + SM_PS + row * 128 + ((col * 2) ^ ((row & 7) << 4))) = f2bf(sv[nt][r]);
                }
            }
            // O = P V  (rows wv*16..+16, 32 dims)
            f32x4 ov[2] = {fzero, fzero};
            #pragma unroll
            for (int ks = 0; ks < 2; ++ks) {
                int m = wv * 16 + l16;
                short8 ap = *(const short8*)(smem + SM_PS + m * 128 +
                                             ((ks * 64 + l4 * 16) ^ ((m & 7) << 4)));
                #pragma unroll
                for (int nt = 0; nt < 2; ++nt) {
                    int d = nt * 16 + l16;
                    short8 bvf = *(const short8*)(smem + SM_VT + d * 128 +
                                                  ((ks * 64 + l4 * 16) ^ ((d & 7) << 4)));
                    ov[nt] = __builtin_amdgcn_mfma_f32_16x16x32_bf16(ap, bvf, ov[nt], 0, 0, 0);
                }
            }
            // O -> ao (bf16, swizzled)
            #pragma unroll
            for (int nt = 0; nt < 2; ++nt) {
                #pragma unroll
                for (int r = 0; r < 4; ++r) {
                    int tok = wv * 16 + l4 * 4 + r;
                    int ch = hh * 32 + nt * 16 + l16;
                    *(ushort_t*)(smem + SM_AO + tok * 1024 + ((ch * 2) ^ ((tok & 7) << 4))) = f2bf(ov[nt][r]);
                }
            }
            __syncthreads();                    // before next head's park reuses scratch
        }
    }

    // ================= proj GEMM: (64x512)@(512x512), wave n-split of 128 =================
    f32x4 pacc[4][8];
    #pragma unroll
    for (int mt = 0; mt < 4; ++mt)
        #pragma unroll
        for (int nt = 0; nt < 8; ++nt) pacc[mt][nt] = fzero;

    int pst_go[8], pst_lo[8];
    #pragma unroll
    for (int l = 0; l < 8; ++l) {
        int idx = l * 256 + tid;
        int n = idx >> 2, cg = idx & 3;
        pst_go[l] = n * 1024 + cg * 16;         // byte off in wp_t
        pst_lo[l] = SM_XS + n * 64 + ((cg * 16) ^ ((n & 3) << 4));
    }
    ushort8 pst[8];
    #pragma unroll
    for (int l = 0; l < 8; ++l)
        pst[l] = *(const ushort8*)((const char*)wp_t + pst_go[l]);

    for (int kc = 0; kc < 16; ++kc) {
        __syncthreads();
        #pragma unroll
        for (int l = 0; l < 8; ++l)
            *(ushort8*)(smem + pst_lo[l]) = pst[l];
        if (kc < 15) {
            #pragma unroll
            for (int l = 0; l < 8; ++l)
                pst[l] = *(const ushort8*)((const char*)wp_t + pst_go[l] + (kc + 1) * 64);
        }
        __syncthreads();
        short8 afr[4];
        #pragma unroll
        for (int mt = 0; mt < 4; ++mt) {
            int m = mt * 16 + l16;
            afr[mt] = *(const short8*)(smem + SM_AO + m * 1024 +
                                       ((kc * 64 + l4 * 16) ^ ((m & 7) << 4)));
        }
        #pragma unroll
        for (int nt = 0; nt < 8; ++nt) {
            int n = wv * 128 + nt * 16 + l16;
            short8 bfr = *(const short8*)(smem + SM_XS + n * 64 +
                                          ((l4 * 16) ^ ((n & 3) << 4)));
            #pragma unroll
            for (int mt = 0; mt < 4; ++mt)
                pacc[mt][nt] = __builtin_amdgcn_mfma_f32_16x16x32_bf16(afr[mt], bfr, pacc[mt][nt], 0, 0, 0);
        }
    }

    // epilogue: +bias, fp32 store with window reverse
    float pb[8];
    #pragma unroll
    for (int nt = 0; nt < 8; ++nt) pb[nt] = proj_b[wv * 128 + nt * 16 + l16];
    #pragma unroll
    for (int mt = 0; mt < 4; ++mt) {
        #pragma unroll
        for (int r = 0; r < 4; ++r) {
            int tok = mt * 16 + l4 * 4 + r;
            int ty = tok >> 3, tx = tok & 7;
            float* orow = outg + ((size_t)((b * 128 + wy * 8 + ty) * 128 + wx * 8 + tx)) * 512
                          + wv * 128 + l16;
            #pragma unroll
            for (int nt = 0; nt < 8; ++nt)
                orow[nt * 16] = pacc[mt][nt][r] + pb[nt];
        }
    }
}

extern "C" void kernel_launch(void* const* d_in, const int* in_sizes, int n_in,
                              void* d_out, int out_size, void* d_ws, size_t ws_size,
                              hipStream_t stream) {
    const float* x      = (const float*)d_in[0];
    const float* qkv_w  = (const float*)d_in[1];
    const float* qkv_b  = (const float*)d_in[2];
    const float* proj_w = (const float*)d_in[3];
    const float* proj_b = (const float*)d_in[4];
    const float* btab   = (const float*)d_in[5];
    float* out = (float*)d_out;

    // workspace: wq_t bf16 [1536][512] (1.5 MiB) + wp_t bf16 [512][512] (0.5 MiB)
    ushort_t* wq_t = (ushort_t*)d_ws;
    ushort_t* wp_t = wq_t + (size_t)1536 * 512;

    hipLaunchKernelGGL(wtrans, dim3(256), dim3(256), 0, stream, qkv_w, proj_w, wq_t, wp_t);
    hipLaunchKernelGGL(swin_mfma, dim3(2048), dim3(256), SMEM_BYTES, stream,
                       x, wq_t, qkv_b, wp_t, proj_b, btab, out);
}

// Round 2
// 1147.195 us; speedup vs baseline: 12.0731x; 1.2180x over previous
//
#include <hip/hip_runtime.h>
#include <stdint.h>
#include <stddef.h>

// Swin WindowAttention, MFMA bf16, barrier-minimized 8-wave version.
// B=8, H=W=128, C=512, WS=8 -> 2048 windows x 64 tokens; NH=16, hd=32.
// Prepass: transpose+cast qkv_w/proj_w to bf16 K-major in d_ws (2 MiB).
// Main: 1 window/block, 512 thr (8 waves, 2/SIMD). B-operands load DIRECT from
// global (L2-resident) into MFMA frags -> zero barriers in QKV and proj phases.

typedef unsigned short ushort_t;
typedef __attribute__((ext_vector_type(8))) unsigned short ushort8;
typedef __attribute__((ext_vector_type(8))) short short8;   // 8 bf16 (4 VGPR) MFMA A/B frag
typedef __attribute__((ext_vector_type(4))) float f32x4;    // MFMA C/D frag

__device__ __forceinline__ float bf2f(ushort_t u) {
    union { unsigned int i; float f; } x; x.i = ((unsigned int)u) << 16; return x.f;
}
__device__ __forceinline__ ushort_t f2bf(float f) {
    union { float f; unsigned int i; } x; x.f = f;
    unsigned int r = x.i + 0x7fffu + ((x.i >> 16) & 1u);    // RNE
    return (ushort_t)(r >> 16);
}

// ---------------- prepass: W (fp32 [c][o]) -> W_t (bf16 [o][c]) ----------------
__global__ __launch_bounds__(256)
void wtrans(const float* __restrict__ qkv_w, const float* __restrict__ proj_w,
            ushort_t* __restrict__ wq_t, ushort_t* __restrict__ wp_t)
{
    __shared__ ushort_t t[64 * 65];
    const int bid = blockIdx.x, tid = threadIdx.x;
    const float* src; ushort_t* dst; int W, to, tc;
    if (bid < 192) { src = qkv_w; dst = wq_t; W = 1536; to = bid % 24; tc = bid / 24; }
    else { int r = bid - 192; src = proj_w; dst = wp_t; W = 512; to = r & 7; tc = r >> 3; }
    for (int l = 0; l < 16; ++l) {
        int idx = l * 256 + tid; int cr = idx >> 6, oc = idx & 63;
        t[oc * 65 + cr] = f2bf(src[(size_t)(tc * 64 + cr) * W + to * 64 + oc]);
    }
    __syncthreads();
    for (int l = 0; l < 16; ++l) {
        int idx = l * 256 + tid; int orr = idx >> 6, cc = idx & 63;
        dst[(size_t)(to * 64 + orr) * 512 + tc * 64 + cc] = t[orr * 65 + cc];
    }
}

// LDS map:
//   xs @0      : X bf16 [64 tok][512 ch], row 1024B, col-byte XOR ((tok&7)<<4)   65536
//   ao @65536  : attn-out bf16 [64][512], same layout                            65536
//   rg @131072 : attention parks, 2 slots x 12288:
//     slot p: qh [64][32] row 64B swz((tok&3)<<4) | kh +4096 same | vt +8192 [32 d][64 tok] row 128B swz((d&7)<<4)
//     ps (per-wave [16][64] row 128B swz((lr&7)<<4), 2KB each) OVERLAYS qh/kh after QK barrier
#define SM_XS 0
#define SM_AO 65536
#define SM_RG 131072
#define SMEM_BYTES 155648

__global__ __launch_bounds__(512, 2)
void swin_mfma(const float* __restrict__ xg,
               const ushort_t* __restrict__ wq_t,
               const float* __restrict__ qkv_b,
               const ushort_t* __restrict__ wp_t,
               const float* __restrict__ proj_b,
               const float* __restrict__ btab,
               float* __restrict__ outg)
{
    extern __shared__ char smem[];
    const int tid = threadIdx.x;
    const int wv = tid >> 6;          // wave 0..7
    const int lane = tid & 63;
    const int l4 = lane >> 4;         // frag k-group
    const int l16 = lane & 15;        // frag row/col
    const int blk = blockIdx.x;
    const int b = blk >> 8, wy = (blk >> 4) & 15, wx = blk & 15;
    const f32x4 fzero = {0.f, 0.f, 0.f, 0.f};
    const float scale = 0.17677669529663687f;   // 1/sqrt(32)

    // ---- stage X window (fp32 -> bf16, swizzled) ----
    #pragma unroll
    for (int l = 0; l < 8; ++l) {
        int idx = l * 512 + tid;
        int t = idx >> 6, v = idx & 63;
        int ty = t >> 3, tx = t & 7;
        size_t goff = ((size_t)((b * 128 + wy * 8 + ty) * 128 + wx * 8 + tx)) * 512 + v * 8;
        float4 a0 = *(const float4*)(xg + goff);
        float4 a1 = *(const float4*)(xg + goff + 4);
        ushort8 d;
        d[0] = f2bf(a0.x); d[1] = f2bf(a0.y); d[2] = f2bf(a0.z); d[3] = f2bf(a0.w);
        d[4] = f2bf(a1.x); d[5] = f2bf(a1.y); d[6] = f2bf(a1.z); d[7] = f2bf(a1.w);
        *(ushort8*)(smem + SM_XS + t * 1024 + ((v * 16) ^ ((t & 7) << 4))) = d;
    }
    __syncthreads();

    // ================= per half: QKV (wave = head), then attention =================
    for (int hi = 0; hi < 2; ++hi) {
        const int h = hi * 8 + wv;
        f32x4 acc[4][6];               // [m-tile][n-tile: q0 q1 k0 k1 v0 v1]
        #pragma unroll
        for (int mt = 0; mt < 4; ++mt)
            #pragma unroll
            for (int nt = 0; nt < 6; ++nt) acc[mt][nt] = fzero;

        // B row pointers: wq_t[o][c], o = (nt>>1)*512 + h*32 + (nt&1)*16 + l16
        const ushort_t* rp[6];
        #pragma unroll
        for (int nt = 0; nt < 6; ++nt)
            rp[nt] = wq_t + (size_t)((nt >> 1) * 512 + h * 32 + (nt & 1) * 16 + l16) * 512 + l4 * 8;

        short8 wb0[6], wb1[6];
        #pragma unroll
        for (int nt = 0; nt < 6; ++nt) wb0[nt] = *(const short8*)(rp[nt]);

        #pragma unroll
        for (int kc = 0; kc < 16; kc += 2) {
            #pragma unroll
            for (int nt = 0; nt < 6; ++nt) wb1[nt] = *(const short8*)(rp[nt] + (kc + 1) * 32);
            short8 af[4];
            #pragma unroll
            for (int mt = 0; mt < 4; ++mt) {
                int m = mt * 16 + l16;
                af[mt] = *(const short8*)(smem + SM_XS + m * 1024 +
                                          ((kc * 64 + l4 * 16) ^ ((m & 7) << 4)));
            }
            __builtin_amdgcn_s_setprio(1);
            #pragma unroll
            for (int nt = 0; nt < 6; ++nt)
                #pragma unroll
                for (int mt = 0; mt < 4; ++mt)
                    acc[mt][nt] = __builtin_amdgcn_mfma_f32_16x16x32_bf16(af[mt], wb0[nt], acc[mt][nt], 0, 0, 0);
            __builtin_amdgcn_s_setprio(0);
            if (kc < 14) {
                #pragma unroll
                for (int nt = 0; nt < 6; ++nt) wb0[nt] = *(const short8*)(rp[nt] + (kc + 2) * 32);
            }
            #pragma unroll
            for (int mt = 0; mt < 4; ++mt) {
                int m = mt * 16 + l16;
                af[mt] = *(const short8*)(smem + SM_XS + m * 1024 +
                                          (((kc + 1) * 64 + l4 * 16) ^ ((m & 7) << 4)));
            }
            __builtin_amdgcn_s_setprio(1);
            #pragma unroll
            for (int nt = 0; nt < 6; ++nt)
                #pragma unroll
                for (int mt = 0; mt < 4; ++mt)
                    acc[mt][nt] = __builtin_amdgcn_mfma_f32_16x16x32_bf16(af[mt], wb1[nt], acc[mt][nt], 0, 0, 0);
            __builtin_amdgcn_s_setprio(0);
        }

        float bq[2], bk2[2], bv2[2];
        #pragma unroll
        for (int i = 0; i < 2; ++i) {
            bq[i]  = qkv_b[         h * 32 + i * 16 + l16];
            bk2[i] = qkv_b[ 512  +  h * 32 + i * 16 + l16];
            bv2[i] = qkv_b[ 1024 +  h * 32 + i * 16 + l16];
        }

        // ---- attention: 4 rounds x 2 heads; waves 0-3 -> slot0 head, 4-7 -> slot1 ----
        for (int r4 = 0; r4 < 4; ++r4) {
            if ((wv >> 1) == r4) {              // owners park Q(scaled)/K/V^T
                char* qb = smem + SM_RG + (wv & 1) * 12288;
                #pragma unroll
                for (int mt = 0; mt < 4; ++mt)
                    #pragma unroll
                    for (int rr = 0; rr < 4; ++rr) {
                        int tok = mt * 16 + l4 * 4 + rr;
                        #pragma unroll
                        for (int i = 0; i < 2; ++i) {
                            int d = i * 16 + l16;
                            *(ushort_t*)(qb + tok * 64 + ((d * 2) ^ ((tok & 3) << 4))) =
                                f2bf((acc[mt][i][rr] + bq[i]) * scale);
                            *(ushort_t*)(qb + 4096 + tok * 64 + ((d * 2) ^ ((tok & 3) << 4))) =
                                f2bf(acc[mt][2 + i][rr] + bk2[i]);
                            *(ushort_t*)(qb + 8192 + d * 128 + ((tok * 2) ^ ((d & 7) << 4))) =
                                f2bf(acc[mt][4 + i][rr] + bv2[i]);
                        }
                    }
            }
            __syncthreads();                    // parks visible
            const int p = wv >> 2;
            const int mtc = wv & 3;
            const int hh = hi * 8 + r4 * 2 + p;
            const char* qb = smem + SM_RG + p * 12288;

            // S = Q K^T (rows mtc*16..+16) + bias
            short8 aq = *(const short8*)(qb + (mtc * 16 + l16) * 64 + ((l4 * 16) ^ ((l16 & 3) << 4)));
            f32x4 sv[4];
            #pragma unroll
            for (int nt = 0; nt < 4; ++nt) {
                short8 bkf = *(const short8*)(qb + 4096 + (nt * 16 + l16) * 64 +
                                              ((l4 * 16) ^ ((l16 & 3) << 4)));
                sv[nt] = __builtin_amdgcn_mfma_f32_16x16x32_bf16(aq, bkf, fzero, 0, 0, 0);
            }
            #pragma unroll
            for (int nt = 0; nt < 4; ++nt) {
                int col = nt * 16 + l16;
                #pragma unroll
                for (int rr = 0; rr < 4; ++rr) {
                    int row = mtc * 16 + l4 * 4 + rr;
                    int dy = (row >> 3) - (col >> 3) + 7;
                    int dx = (row & 7)  - (col & 7)  + 7;
                    sv[nt][rr] += btab[(dy * 15 + dx) * 16 + hh];
                }
            }
            // wave-parallel softmax over l16 lanes
            #pragma unroll
            for (int rr = 0; rr < 4; ++rr) {
                float mx = fmaxf(fmaxf(sv[0][rr], sv[1][rr]), fmaxf(sv[2][rr], sv[3][rr]));
                mx = fmaxf(mx, __shfl_xor(mx, 1));
                mx = fmaxf(mx, __shfl_xor(mx, 2));
                mx = fmaxf(mx, __shfl_xor(mx, 4));
                mx = fmaxf(mx, __shfl_xor(mx, 8));
                float sm = 0.f;
                #pragma unroll
                for (int nt = 0; nt < 4; ++nt) { sv[nt][rr] = __expf(sv[nt][rr] - mx); sm += sv[nt][rr]; }
                sm += __shfl_xor(sm, 1);
                sm += __shfl_xor(sm, 2);
                sm += __shfl_xor(sm, 4);
                sm += __shfl_xor(sm, 8);
                float inv = 1.f / sm;
                #pragma unroll
                for (int nt = 0; nt < 4; ++nt) sv[nt][rr] *= inv;
            }
            __syncthreads();                    // all qh/kh reads done before ps overlay
            char* psb = smem + SM_RG + ((wv < 4) ? wv * 2048 : 12288 + (wv - 4) * 2048);
            #pragma unroll
            for (int nt = 0; nt < 4; ++nt)
                #pragma unroll
                for (int rr = 0; rr < 4; ++rr) {
                    int lr = l4 * 4 + rr;
                    *(ushort_t*)(psb + lr * 128 + (((nt * 16 + l16) * 2) ^ ((lr & 7) << 4))) =
                        f2bf(sv[nt][rr]);
                }
            // O = P V (own 16 rows x 32 dims)
            f32x4 ov[2] = {fzero, fzero};
            #pragma unroll
            for (int ks = 0; ks < 2; ++ks) {
                short8 ap = *(const short8*)(psb + l16 * 128 + ((ks * 64 + l4 * 16) ^ ((l16 & 7) << 4)));
                #pragma unroll
                for (int ntd = 0; ntd < 2; ++ntd) {
                    short8 bvf = *(const short8*)(qb + 8192 + (ntd * 16 + l16) * 128 +
                                                  ((ks * 64 + l4 * 16) ^ ((l16 & 7) << 4)));
                    ov[ntd] = __builtin_amdgcn_mfma_f32_16x16x32_bf16(ap, bvf, ov[ntd], 0, 0, 0);
                }
            }
            #pragma unroll
            for (int ntd = 0; ntd < 2; ++ntd)
                #pragma unroll
                for (int rr = 0; rr < 4; ++rr) {
                    int tok = mtc * 16 + l4 * 4 + rr;
                    int ch = hh * 32 + ntd * 16 + l16;
                    *(ushort_t*)(smem + SM_AO + tok * 1024 + ((ch * 2) ^ ((tok & 7) << 4))) =
                        f2bf(ov[ntd][rr]);
                }
            __syncthreads();                    // ps/vt reads done before next round's parks
        }
    }

    // ================= proj GEMM: (64x512)@(512x512), wave owns 64 out-cols =================
    f32x4 pacc[4][4];
    #pragma unroll
    for (int mt = 0; mt < 4; ++mt)
        #pragma unroll
        for (int nt = 0; nt < 4; ++nt) pacc[mt][nt] = fzero;

    const ushort_t* pp[4];
    #pragma unroll
    for (int nt = 0; nt < 4; ++nt)
        pp[nt] = wp_t + (size_t)(wv * 64 + nt * 16 + l16) * 512 + l4 * 8;

    short8 pc0[4], pc1[4];
    #pragma unroll
    for (int nt = 0; nt < 4; ++nt) pc0[nt] = *(const short8*)(pp[nt]);

    #pragma unroll
    for (int kc = 0; kc < 16; kc += 2) {
        #pragma unroll
        for (int nt = 0; nt < 4; ++nt) pc1[nt] = *(const short8*)(pp[nt] + (kc + 1) * 32);
        short8 af[4];
        #pragma unroll
        for (int mt = 0; mt < 4; ++mt) {
            int m = mt * 16 + l16;
            af[mt] = *(const short8*)(smem + SM_AO + m * 1024 +
                                      ((kc * 64 + l4 * 16) ^ ((m & 7) << 4)));
        }
        __builtin_amdgcn_s_setprio(1);
        #pragma unroll
        for (int nt = 0; nt < 4; ++nt)
            #pragma unroll
            for (int mt = 0; mt < 4; ++mt)
                pacc[mt][nt] = __builtin_amdgcn_mfma_f32_16x16x32_bf16(af[mt], pc0[nt], pacc[mt][nt], 0, 0, 0);
        __builtin_amdgcn_s_setprio(0);
        if (kc < 14) {
            #pragma unroll
            for (int nt = 0; nt < 4; ++nt) pc0[nt] = *(const short8*)(pp[nt] + (kc + 2) * 32);
        }
        #pragma unroll
        for (int mt = 0; mt < 4; ++mt) {
            int m = mt * 16 + l16;
            af[mt] = *(const short8*)(smem + SM_AO + m * 1024 +
                                      (((kc + 1) * 64 + l4 * 16) ^ ((m & 7) << 4)));
        }
        __builtin_amdgcn_s_setprio(1);
        #pragma unroll
        for (int nt = 0; nt < 4; ++nt)
            #pragma unroll
            for (int mt = 0; mt < 4; ++mt)
                pacc[mt][nt] = __builtin_amdgcn_mfma_f32_16x16x32_bf16(af[mt], pc1[nt], pacc[mt][nt], 0, 0, 0);
        __builtin_amdgcn_s_setprio(0);
    }

    // epilogue: +bias, fp32 store with window reverse
    float pb[4];
    #pragma unroll
    for (int nt = 0; nt < 4; ++nt) pb[nt] = proj_b[wv * 64 + nt * 16 + l16];
    #pragma unroll
    for (int mt = 0; mt < 4; ++mt) {
        #pragma unroll
        for (int rr = 0; rr < 4; ++rr) {
            int tok = mt * 16 + l4 * 4 + rr;
            int ty = tok >> 3, tx = tok & 7;
            float* orow = outg + ((size_t)((b * 128 + wy * 8 + ty) * 128 + wx * 8 + tx)) * 512
                          + wv * 64 + l16;
            #pragma unroll
            for (int nt = 0; nt < 4; ++nt)
                orow[nt * 16] = pacc[mt][nt][rr] + pb[nt];
        }
    }
}

extern "C" void kernel_launch(void* const* d_in, const int* in_sizes, int n_in,
                              void* d_out, int out_size, void* d_ws, size_t ws_size,
                              hipStream_t stream) {
    const float* x      = (const float*)d_in[0];
    const float* qkv_w  = (const float*)d_in[1];
    const float* qkv_b  = (const float*)d_in[2];
    const float* proj_w = (const float*)d_in[3];
    const float* proj_b = (const float*)d_in[4];
    const float* btab   = (const float*)d_in[5];
    float* out = (float*)d_out;

    // workspace: wq_t bf16 [1536][512] (1.5 MiB) + wp_t bf16 [512][512] (0.5 MiB)
    ushort_t* wq_t = (ushort_t*)d_ws;
    ushort_t* wp_t = wq_t + (size_t)1536 * 512;

    hipLaunchKernelGGL(wtrans, dim3(256), dim3(256), 0, stream, qkv_w, proj_w, wq_t, wp_t);
    hipLaunchKernelGGL(swin_mfma, dim3(2048), dim3(512), SMEM_BYTES, stream,
                       x, wq_t, qkv_b, wp_t, proj_b, btab, out);
}